// Round 2
// baseline (420.543 us; speedup 1.0000x reference)
//
#include <hip/hip_runtime.h>
#include <stdint.h>

#define NGT_MAX 128
#define CAND_CAP 8192
#define SUB_CAP 2048

// ---- threefry2x32 (exact JAX semantics) ----
__host__ __device__ inline void tf2x32(uint32_t k0, uint32_t k1, uint32_t c0, uint32_t c1,
                                       uint32_t& o0, uint32_t& o1) {
  uint32_t ks[3] = {k0, k1, k0 ^ k1 ^ 0x1BD11BDAu};
  uint32_t x0 = c0 + ks[0];
  uint32_t x1 = c1 + ks[1];
  const int rot[2][4] = {{13, 15, 26, 6}, {17, 29, 16, 24}};
#pragma unroll
  for (int i = 0; i < 5; ++i) {
#pragma unroll
    for (int j = 0; j < 4; ++j) {
      x0 += x1;
      int r = rot[i & 1][j];
      x1 = (x1 << r) | (x1 >> (32 - r));
      x1 ^= x0;
    }
    x0 += ks[(i + 1) % 3];
    x1 += ks[(i + 2) % 3] + (uint32_t)(i + 1);
  }
  o0 = x0; o1 = x1;
}

// Partitionable threefry random_bits: element i of uniform(key,(N,)) uses block
// (hi,lo)=(0,i); 32-bit draw = o0 ^ o1 (XOR fold). uniform = bitcast(bits>>9 |
// 0x3f800000) - 1, monotone in bits>>9. Selection key = (bits>>9, index) lex
// (stable argsort tiebreak).
__device__ inline uint64_t sel_key(uint32_t i, uint32_t ka, uint32_t kb) {
  uint32_t o0, o1;
  tf2x32(ka, kb, 0u, i, o0, o1);
  uint32_t bits = o0 ^ o1;
  return ((uint64_t)(bits >> 9) << 32) | (uint64_t)i;
}

// ---- kernels ----
__global__ void k_init(uint32_t* counters, uint32_t* ggmax) {
  int t = threadIdx.x;
  if (t < 16) counters[t] = 0u;
  if (t < NGT_MAX) ggmax[t] = 0x407FFFFFu;  // order-map of -1.0f
}

// Pass 1: per-gt max of iou_m (order-preserving u32 map + atomicMax) and bbox targets.
__global__ void __launch_bounds__(256)
k_gtmax_targets(const float4* __restrict__ anc, const float* __restrict__ img,
                const float4* __restrict__ gt, int N, int R,
                uint32_t* __restrict__ ggmax, float4* __restrict__ tgt) {
  __shared__ float4 sgt[NGT_MAX];
  __shared__ float sarea[NGT_MAX];
  __shared__ uint32_t sgmax[NGT_MAX];
  const int t = threadIdx.x;
  if (t < R) {
    float4 g = gt[t];
    sgt[t] = g;
    {
#pragma clang fp contract(off)
      sarea[t] = (g.z - g.x + 1.0f) * (g.w - g.y + 1.0f);
    }
    sgmax[t] = 0x407FFFFFu;
  }
  __syncthreads();
  const int i = blockIdx.x * blockDim.x + t;
  const float H = img[0], W = img[1];
  if (i < N) {
    float4 a = anc[i];
    bool inside = (a.x >= 0.0f) && (a.y >= 0.0f) && (a.z < W) && (a.w < H);
    float area_a;
    {
#pragma clang fp contract(off)
      area_a = (a.z - a.x + 1.0f) * (a.w - a.y + 1.0f);
    }
    float vmax = -1.0f;
    for (int g = 0; g < R; ++g) {
      float4 gb = sgt[g];
      float v;
      {
#pragma clang fp contract(off)
        float iw = fminf(a.z, gb.z) - fmaxf(a.x, gb.x) + 1.0f;
        float ih = fminf(a.w, gb.w) - fmaxf(a.y, gb.y) + 1.0f;
        float inter = fmaxf(iw, 0.0f) * fmaxf(ih, 0.0f);
        v = inter / (area_a + sarea[g] - inter);
      }
      v = inside ? v : -1.0f;
      vmax = fmaxf(vmax, v);
      uint32_t u = __float_as_uint(v);
      uint32_t mv = (u & 0x80000000u) ? ~u : (u | 0x80000000u);
      if (mv > sgmax[g]) atomicMax(&sgmax[g], mv);
    }
    float4 o = make_float4(0.f, 0.f, 0.f, 0.f);
    if (inside) {
      int idx = (int)vmax;  // trunc toward zero, faithful to astype(int32)
      idx = idx < 0 ? 0 : idx;
      idx = idx > R - 1 ? R - 1 : idx;
      float4 gb = sgt[idx];
      {
#pragma clang fp contract(off)
        float aw = a.z - a.x + 1.0f;
        float ah = a.w - a.y + 1.0f;
        float acx = a.x + 0.5f * aw;
        float acy = a.y + 0.5f * ah;
        float gw = gb.z - gb.x + 1.0f;
        float gh = gb.w - gb.y + 1.0f;
        float gcx = gb.x + 0.5f * gw;
        float gcy = gb.y + 0.5f * gh;
        o.x = (gcx - acx) / aw;
        o.y = (gcy - acy) / ah;
        o.z = logf(gw / aw);
        o.w = logf(gh / ah);
      }
    }
    tgt[i] = o;
  }
  __syncthreads();
  if (t < R) atomicMax(&ggmax[t], sgmax[t]);
}

// Pass 2: base labels (-1/0/1 from thresholds) + gather tie-set candidates.
__global__ void __launch_bounds__(256)
k_labels_cand(const float4* __restrict__ anc, const float* __restrict__ img,
              const float4* __restrict__ gt, int N, int R,
              const uint32_t* __restrict__ ggmax,
              float* __restrict__ LBL, uint64_t* __restrict__ candList,
              uint32_t* __restrict__ counters, uint32_t ka, uint32_t kb) {
  __shared__ float4 sgt[NGT_MAX];
  __shared__ float sarea[NGT_MAX];
  __shared__ float sgmaxf[NGT_MAX];
  const int t = threadIdx.x;
  if (t < R) {
    float4 g = gt[t];
    sgt[t] = g;
    {
#pragma clang fp contract(off)
      sarea[t] = (g.z - g.x + 1.0f) * (g.w - g.y + 1.0f);
    }
    uint32_t u = ggmax[t];
    sgmaxf[t] = (u & 0x80000000u) ? __uint_as_float(u & 0x7FFFFFFFu) : __uint_as_float(~u);
  }
  __syncthreads();
  const int i = blockIdx.x * blockDim.x + t;
  if (i >= N) return;
  const float H = img[0], W = img[1];
  float4 a = anc[i];
  bool inside = (a.x >= 0.0f) && (a.y >= 0.0f) && (a.z < W) && (a.w < H);
  if (!inside) { LBL[i] = -1.0f; return; }
  float area_a;
  {
#pragma clang fp contract(off)
    area_a = (a.z - a.x + 1.0f) * (a.w - a.y + 1.0f);
  }
  float vmax = -1.0f;
  bool cand = false;
  for (int g = 0; g < R; ++g) {
    float4 gb = sgt[g];
    float v;
    {
#pragma clang fp contract(off)
      float iw = fminf(a.z, gb.z) - fmaxf(a.x, gb.x) + 1.0f;
      float ih = fminf(a.w, gb.w) - fmaxf(a.y, gb.y) + 1.0f;
      float inter = fmaxf(iw, 0.0f) * fmaxf(ih, 0.0f);
      v = inter / (area_a + sarea[g] - inter);
    }
    cand = cand || (v == sgmaxf[g]);  // bitwise-identical recompute of pass-1 values
    vmax = fmaxf(vmax, v);
  }
  float lbl = -1.0f;
  if (vmax < 0.3f) lbl = 0.0f;
  if (vmax >= 0.7f) lbl = 1.0f;
  LBL[i] = lbl;
  if (cand) {
    uint32_t p = atomicAdd(&counters[0], 1u);
    if (p < CAND_CAP) candList[p] = sel_key((uint32_t)i, ka, kb);
  }
}

// keep_at_most(cand, R): rank-select k smallest (value,index), set kept -> 1.
__global__ void k_cand_select(const uint64_t* __restrict__ candList,
                              const uint32_t* __restrict__ counters,
                              float* __restrict__ LBL, int R) {
  uint32_t C = counters[0];
  if (C > CAND_CAP) C = CAND_CAP;
  const uint32_t k = (uint32_t)R;
  for (uint32_t s = threadIdx.x; s < C; s += blockDim.x) {
    uint64_t key = candList[s];
    bool keep = true;
    if (C > k) {
      uint32_t rank = 0;
      for (uint32_t j = 0; j < C; ++j) rank += (candList[j] < key) ? 1u : 0u;
      keep = (rank < k);
    }
    if (keep) LBL[(uint32_t)key] = 1.0f;
  }
}

// gather indices with LBL==target into list with their selection keys
__global__ void __launch_bounds__(256)
k_gather(const float* __restrict__ LBL, int N, float target,
         uint64_t* __restrict__ list, uint32_t* __restrict__ counter,
         uint32_t ka, uint32_t kb) {
  int i = blockIdx.x * blockDim.x + threadIdx.x;
  if (i >= N) return;
  if (LBL[i] == target) {
    uint32_t p = atomicAdd(counter, 1u);
    list[p] = sel_key((uint32_t)i, ka, kb);
  }
}

// exact k-smallest select over M items: 2048-bin histogram on top 11 bits of the
// 23-bit uniform key, then exact in-bin ranking. Non-kept -> LBL = -1.
// mode 0: fg (k=128, writes n_fg=counters[3]); mode 1: bg (k=256-n_fg).
__global__ void __launch_bounds__(1024)
k_select(const uint64_t* __restrict__ list, uint32_t* __restrict__ counters,
         int cntIdx, int mode, float* __restrict__ LBL) {
  __shared__ uint32_t hist[2048];
  __shared__ uint64_t sub[SUB_CAP];
  __shared__ uint32_t subcnt, sbinb, srneed;
  const uint32_t M = counters[cntIdx];
  const uint32_t k = (mode == 0) ? 128u : (256u - counters[3]);
  if (mode == 0 && threadIdx.x == 0) counters[3] = (M < 128u) ? M : 128u;
  if (M <= k) return;  // keep all (uniform branch)
  for (uint32_t b = threadIdx.x; b < 2048; b += blockDim.x) hist[b] = 0u;
  if (threadIdx.x == 0) subcnt = 0u;
  __syncthreads();
  for (uint32_t j = threadIdx.x; j < M; j += blockDim.x) {
    uint32_t top = ((uint32_t)(list[j] >> 32)) >> 12;
    atomicAdd(&hist[top], 1u);
  }
  __syncthreads();
  if (threadIdx.x == 0) {
    uint32_t cum = 0u;
    for (uint32_t b = 0; b < 2048; ++b) {
      uint32_t h = hist[b];
      if (cum + h >= k) { sbinb = b; srneed = k - cum; break; }
      cum += h;
    }
  }
  __syncthreads();
  const uint32_t binb = sbinb, rneed = srneed;
  for (uint32_t j = threadIdx.x; j < M; j += blockDim.x) {
    uint64_t key = list[j];
    uint32_t top = ((uint32_t)(key >> 32)) >> 12;
    if (top > binb) {
      LBL[(uint32_t)key] = -1.0f;
    } else if (top == binb) {
      uint32_t p = atomicAdd(&subcnt, 1u);
      if (p < SUB_CAP) sub[p] = key;
    }
  }
  __syncthreads();
  uint32_t c = subcnt < SUB_CAP ? subcnt : SUB_CAP;
  for (uint32_t s = threadIdx.x; s < c; s += blockDim.x) {
    uint64_t key = sub[s];
    uint32_t rank = 0u;
    for (uint32_t j = 0; j < c; ++j) rank += (sub[j] < key) ? 1u : 0u;
    if (rank >= rneed) LBL[(uint32_t)key] = -1.0f;
  }
}

extern "C" void kernel_launch(void* const* d_in, const int* in_sizes, int n_in,
                              void* d_out, int out_size, void* d_ws, size_t ws_size,
                              hipStream_t stream) {
  (void)n_in; (void)out_size; (void)ws_size;
  const int N = in_sizes[0] / 4;  // 262144 anchors
  const int R = in_sizes[2] / 4;  // 100 gt boxes
  const float4* anc = (const float4*)d_in[0];
  const float* img = (const float*)d_in[1];
  const float4* gtb = (const float4*)d_in[2];
  float* LBL = (float*)d_out;                       // labels (N)
  float4* TGT = (float4*)((float*)d_out + N);       // bbox targets (N,4)

  uint8_t* ws = (uint8_t*)d_ws;
  uint32_t* counters = (uint32_t*)ws;                          // 16 u32
  uint32_t* ggmax = (uint32_t*)(ws + 64);                      // 128 u32 (order-mapped)
  uint64_t* candList = (uint64_t*)(ws + 1024);                 // CAND_CAP u64
  uint64_t* list = (uint64_t*)(ws + 1024 + CAND_CAP * 8);      // N u64

  // Partitionable ("foldlike") jax.random.split(key(42), 3):
  // key_j = (o0, o1) of threefry((0,42), (0, j)).
  uint32_t k1a, k1b, k2a, k2b, k3a, k3b;
  tf2x32(0u, 42u, 0u, 0u, k1a, k1b);
  tf2x32(0u, 42u, 0u, 1u, k2a, k2b);
  tf2x32(0u, 42u, 0u, 2u, k3a, k3b);

  const int blocks = (N + 255) / 256;
  k_init<<<1, 128, 0, stream>>>(counters, ggmax);
  k_gtmax_targets<<<blocks, 256, 0, stream>>>(anc, img, gtb, N, R, ggmax, TGT);
  k_labels_cand<<<blocks, 256, 0, stream>>>(anc, img, gtb, N, R, ggmax, LBL,
                                            candList, counters, k1a, k1b);
  k_cand_select<<<1, 256, 0, stream>>>(candList, counters, LBL, R);
  k_gather<<<blocks, 256, 0, stream>>>(LBL, N, 1.0f, list, &counters[1], k2a, k2b);
  k_select<<<1, 1024, 0, stream>>>(list, counters, 1, 0, LBL);
  k_gather<<<blocks, 256, 0, stream>>>(LBL, N, 0.0f, list, &counters[2], k3a, k3b);
  k_select<<<1, 1024, 0, stream>>>(list, counters, 2, 1, LBL);
}

// Round 3
// 202.029 us; speedup vs baseline: 2.0816x; 2.0816x over previous
//
#include <hip/hip_runtime.h>
#include <stdint.h>

#define NGT_MAX 128
#define CAND_CAP 8192
#define FILT_CAP 16384
#define SUB_CAP 2048

// counters: [0]=cand count, [1]=fg total, [2]=bg total, [3]=n_fg, [4]=fg filt, [5]=bg filt

// ---- threefry2x32 (exact JAX semantics) ----
__host__ __device__ inline void tf2x32(uint32_t k0, uint32_t k1, uint32_t c0, uint32_t c1,
                                       uint32_t& o0, uint32_t& o1) {
  uint32_t ks[3] = {k0, k1, k0 ^ k1 ^ 0x1BD11BDAu};
  uint32_t x0 = c0 + ks[0];
  uint32_t x1 = c1 + ks[1];
  const int rot[2][4] = {{13, 15, 26, 6}, {17, 29, 16, 24}};
#pragma unroll
  for (int i = 0; i < 5; ++i) {
#pragma unroll
    for (int j = 0; j < 4; ++j) {
      x0 += x1;
      int r = rot[i & 1][j];
      x1 = (x1 << r) | (x1 >> (32 - r));
      x1 ^= x0;
    }
    x0 += ks[(i + 1) % 3];
    x1 += ks[(i + 2) % 3] + (uint32_t)(i + 1);
  }
  o0 = x0; o1 = x1;
}

// Partitionable threefry: element i of uniform(key,(N,)) uses block (0,i); draw = o0^o1.
// Selection key = (bits>>9, index) lexicographic (stable argsort tiebreak).
__device__ inline uint64_t sel_key(uint32_t i, uint32_t ka, uint32_t kb) {
  uint32_t o0, o1;
  tf2x32(ka, kb, 0u, i, o0, o1);
  uint32_t bits = o0 ^ o1;
  return ((uint64_t)(bits >> 9) << 32) | (uint64_t)i;
}

__device__ inline uint32_t fmap(float v) {
  uint32_t u = __float_as_uint(v);
  return (u & 0x80000000u) ? ~u : (u | 0x80000000u);
}
__device__ inline float funmap(uint32_t m) {
  return (m & 0x80000000u) ? __uint_as_float(m & 0x7FFFFFFFu) : __uint_as_float(~m);
}

__global__ void k_init(uint32_t* counters, uint32_t* flags) {
  int t = threadIdx.x;
  if (t < 16) counters[t] = 0u;
  if (t < 64) flags[t] = 0u;
}

// Single IoU pass: per-anchor vmax -> base labels + bbox targets; per-gt wave max via
// shfl butterfly (no loads/atomics in the hot loop) -> per-block pmax table; fg/bg counts.
__global__ void __launch_bounds__(256)
k_main(const float4* __restrict__ anc, const float* __restrict__ img,
       const float4* __restrict__ gt, int N, int R,
       uint32_t* __restrict__ pmax, float* __restrict__ LBL, float4* __restrict__ TGT,
       uint32_t* __restrict__ counters) {
  __shared__ float4 sgt[NGT_MAX];
  __shared__ float sarea[NGT_MAX];
  __shared__ uint32_t swmax[4][NGT_MAX];
  __shared__ uint32_t scnt[2];
  const int t = threadIdx.x;
  if (t < 2) scnt[t] = 0u;
  if (t < R) {
    float4 g = gt[t];
    sgt[t] = g;
    {
#pragma clang fp contract(off)
      sarea[t] = (g.z - g.x + 1.0f) * (g.w - g.y + 1.0f);
    }
  }
  __syncthreads();
  const int wid = t >> 6, lane = t & 63;
  const int i = blockIdx.x * 256 + t;  // N is a multiple of 256
  const float H = img[0], W = img[1];
  float4 a = anc[i];
  bool inside = (a.x >= 0.0f) && (a.y >= 0.0f) && (a.z < W) && (a.w < H);
  float area_a;
  {
#pragma clang fp contract(off)
    area_a = (a.z - a.x + 1.0f) * (a.w - a.y + 1.0f);
  }
  float vmax = -1.0f;
#pragma unroll 4
  for (int g = 0; g < R; ++g) {
    float4 gb = sgt[g];
    float v;
    {
#pragma clang fp contract(off)
      float iw = fminf(a.z, gb.z) - fmaxf(a.x, gb.x) + 1.0f;
      float ih = fminf(a.w, gb.w) - fmaxf(a.y, gb.y) + 1.0f;
      float inter = fmaxf(iw, 0.0f) * fmaxf(ih, 0.0f);
      v = inter / (area_a + sarea[g] - inter);
    }
    v = inside ? v : -1.0f;
    vmax = fmaxf(vmax, v);
    // wave-64 butterfly max (values are -1 or [0,1], never NaN/-0)
    float wm = v;
#pragma unroll
    for (int off = 32; off > 0; off >>= 1) wm = fmaxf(wm, __shfl_xor(wm, off));
    if (lane == 0) swmax[wid][g] = fmap(wm);
  }
  // base labels
  float lbl = -1.0f;
  if (inside) {
    if (vmax < 0.3f) lbl = 0.0f;
    if (vmax >= 0.7f) lbl = 1.0f;
  }
  LBL[i] = lbl;
  // per-block fg/bg counts (ballot + 1 LDS atomic per wave)
  unsigned long long bf = __ballot(lbl == 1.0f);
  unsigned long long bb = __ballot(lbl == 0.0f);
  if (lane == 0) {
    atomicAdd(&scnt[0], (uint32_t)__popcll(bf));
    atomicAdd(&scnt[1], (uint32_t)__popcll(bb));
  }
  // bbox targets (faithful gt[clip(int32(max_ov))])
  float4 o = make_float4(0.f, 0.f, 0.f, 0.f);
  if (inside) {
    int idx = (int)vmax;
    idx = idx < 0 ? 0 : idx;
    idx = idx > R - 1 ? R - 1 : idx;
    float4 gb = sgt[idx];
    {
#pragma clang fp contract(off)
      float aw = a.z - a.x + 1.0f;
      float ah = a.w - a.y + 1.0f;
      float acx = a.x + 0.5f * aw;
      float acy = a.y + 0.5f * ah;
      float gw = gb.z - gb.x + 1.0f;
      float gh = gb.w - gb.y + 1.0f;
      float gcx = gb.x + 0.5f * gw;
      float gcy = gb.y + 0.5f * gh;
      o.x = (gcx - acx) / aw;
      o.y = (gcy - acy) / ah;
      o.z = logf(gw / aw);
      o.w = logf(gh / ah);
    }
  }
  TGT[i] = o;
  __syncthreads();
  if (t < R) {
    uint32_t m = max(max(swmax[0][t], swmax[1][t]), max(swmax[2][t], swmax[3][t]));
    pmax[blockIdx.x * R + t] = m;
  }
  if (t == 0) {
    atomicAdd(&counters[1], scnt[0]);
    atomicAdd(&counters[2], scnt[1]);
  }
}

// Per-gt global max over the per-block table + flag blocks achieving it.
__global__ void __launch_bounds__(256)
k_reduce(const uint32_t* __restrict__ pmax, int NB, int R,
         uint32_t* __restrict__ gmaxu, float* __restrict__ gmaxf,
         uint32_t* __restrict__ flags) {
  __shared__ uint32_t red[256];
  const int g = blockIdx.x;
  const int t = threadIdx.x;
  uint32_t m = 0u;
  for (int j = t; j < NB; j += 256) m = max(m, pmax[j * R + g]);
  red[t] = m;
  __syncthreads();
  for (int s = 128; s > 0; s >>= 1) {
    if (t < s) red[t] = max(red[t], red[t + s]);
    __syncthreads();
  }
  uint32_t gm = red[0];
  if (t == 0) { gmaxu[g] = gm; gmaxf[g] = funmap(gm); }
  for (int j = t; j < NB; j += 256)
    if (pmax[j * R + g] == gm) atomicOr(&flags[j >> 5], 1u << (j & 31));
}

// Recompute IoU rows only in flagged blocks; bit-exact tie check vs gmaxf.
__global__ void __launch_bounds__(256)
k_cand(const float4* __restrict__ anc, const float* __restrict__ img,
       const float4* __restrict__ gt, int N, int R,
       const uint32_t* __restrict__ flags, const float* __restrict__ gmaxf,
       uint64_t* __restrict__ candList, uint32_t* __restrict__ counters,
       uint32_t ka, uint32_t kb) {
  const int b = blockIdx.x;
  if (!((flags[b >> 5] >> (b & 31)) & 1u)) return;
  __shared__ float4 sgt[NGT_MAX];
  __shared__ float sarea[NGT_MAX];
  __shared__ float sgm[NGT_MAX];
  const int t = threadIdx.x;
  if (t < R) {
    float4 g = gt[t];
    sgt[t] = g;
    {
#pragma clang fp contract(off)
      sarea[t] = (g.z - g.x + 1.0f) * (g.w - g.y + 1.0f);
    }
    sgm[t] = gmaxf[t];
  }
  __syncthreads();
  const int i = b * 256 + t;
  const float H = img[0], W = img[1];
  float4 a = anc[i];
  bool inside = (a.x >= 0.0f) && (a.y >= 0.0f) && (a.z < W) && (a.w < H);
  if (!inside) return;
  float area_a;
  {
#pragma clang fp contract(off)
    area_a = (a.z - a.x + 1.0f) * (a.w - a.y + 1.0f);
  }
  bool cand = false;
  for (int g = 0; g < R; ++g) {
    float4 gb = sgt[g];
    float v;
    {
#pragma clang fp contract(off)
      float iw = fminf(a.z, gb.z) - fmaxf(a.x, gb.x) + 1.0f;
      float ih = fminf(a.w, gb.w) - fmaxf(a.y, gb.y) + 1.0f;
      float inter = fmaxf(iw, 0.0f) * fmaxf(ih, 0.0f);
      v = inter / (area_a + sarea[g] - inter);
    }
    cand = cand || (v == sgm[g]);
  }
  if (cand) {
    uint32_t p = atomicAdd(&counters[0], 1u);
    if (p < CAND_CAP) candList[p] = sel_key((uint32_t)i, ka, kb);
  }
}

// keep_at_most(cand, R): rank-select k smallest; kept -> label 1 (+ fg/bg count fixup).
__global__ void k_cand_select(const uint64_t* __restrict__ candList,
                              uint32_t* __restrict__ counters,
                              float* __restrict__ LBL, int R) {
  uint32_t C = counters[0];
  if (C > CAND_CAP) C = CAND_CAP;
  const uint32_t k = (uint32_t)R;
  for (uint32_t s = threadIdx.x; s < C; s += blockDim.x) {
    uint64_t key = candList[s];
    bool keep = true;
    if (C > k) {
      uint32_t rank = 0;
      for (uint32_t j = 0; j < C; ++j) rank += (candList[j] < key) ? 1u : 0u;
      keep = (rank < k);
    }
    if (keep) {
      uint32_t i = (uint32_t)key;
      float old = LBL[i];
      LBL[i] = 1.0f;
      if (old != 1.0f) atomicAdd(&counters[1], 1u);
      if (old == 0.0f) atomicSub(&counters[2], 1u);
    }
  }
}

// Gather LBL==target anchors: those with key >= T are provably not in the k smallest
// -> LBL=-1 immediately; the rest (expected ~32k of them ~= 4-8k) go to the filtered list.
__global__ void __launch_bounds__(256)
k_gather(float* __restrict__ LBL, int N, float target,
         uint32_t* __restrict__ counters, int totIdx, int filtIdx, int kBase, int mode,
         uint64_t* __restrict__ flist, uint32_t ka, uint32_t kb) {
  int i = blockIdx.x * blockDim.x + threadIdx.x;
  if (i >= N) return;
  if (LBL[i] != target) return;
  uint32_t M = counters[totIdx];
  int k = kBase - (mode ? (int)counters[3] : 0);
  if ((int)M <= k) return;  // keep all
  uint64_t key = sel_key((uint32_t)i, ka, kb);
  uint32_t keyhi = (uint32_t)(key >> 32);
  uint64_t T = ((uint64_t)(uint32_t)(k * 32) << 23) / (uint64_t)M;
  if (T > (1u << 23)) T = (1u << 23);
  if ((uint64_t)keyhi >= T) {
    LBL[i] = -1.0f;
  } else {
    uint32_t p = atomicAdd(&counters[filtIdx], 1u);
    if (p < FILT_CAP) flist[p] = key;
  }
}

// Exact k-smallest over the filtered list: 1024-bin hist + parallel scan + in-bin rank.
__global__ void __launch_bounds__(1024)
k_sel(const uint64_t* __restrict__ flist, uint32_t* __restrict__ counters,
      int totIdx, int filtIdx, int kBase, int mode, float* __restrict__ LBL) {
  __shared__ uint32_t h[1024], c0[1024], c1[1024];
  __shared__ uint64_t sub[SUB_CAP];
  __shared__ uint32_t subcnt, sbinb, srneed;
  const int t = threadIdx.x;
  uint32_t M = counters[totIdx];
  int k = kBase - (mode ? (int)counters[3] : 0);
  if (mode == 0 && t == 0) counters[3] = (M < 128u) ? M : 128u;
  if ((int)M <= k) return;
  uint32_t Mf = counters[filtIdx];
  if (Mf > FILT_CAP) Mf = FILT_CAP;
  uint64_t T = ((uint64_t)(uint32_t)(k * 32) << 23) / (uint64_t)M;
  if (T > (1u << 23)) T = (1u << 23);
  uint32_t Tm1 = (T == 0) ? 0u : (uint32_t)(T - 1);
  int bl = (Tm1 == 0) ? 0 : (32 - __clz(Tm1));
  int shift = bl > 10 ? bl - 10 : 0;
  h[t] = 0u;
  if (t == 0) { subcnt = 0u; sbinb = 0u; srneed = 0u; }
  __syncthreads();
  for (uint32_t j = t; j < Mf; j += 1024)
    atomicAdd(&h[(uint32_t)(flist[j] >> 32) >> shift], 1u);
  __syncthreads();
  // inclusive scan (Hillis-Steele, ping-pong)
  c0[t] = h[t];
  __syncthreads();
  uint32_t* src = c0;
  uint32_t* dst = c1;
  for (int d = 1; d < 1024; d <<= 1) {
    uint32_t v = src[t];
    if (t >= d) v += src[t - d];
    dst[t] = v;
    __syncthreads();
    uint32_t* tmp = src; src = dst; dst = tmp;
  }
  uint32_t inc = src[t];
  uint32_t exc = inc - h[t];
  if (k > 0 && exc < (uint32_t)k && inc >= (uint32_t)k) { sbinb = (uint32_t)t; srneed = (uint32_t)k - exc; }
  __syncthreads();
  const uint32_t binb = sbinb, rneed = srneed;
  for (uint32_t j = t; j < Mf; j += 1024) {
    uint64_t key = flist[j];
    uint32_t bin = (uint32_t)(key >> 32) >> shift;
    if (bin > binb) {
      LBL[(uint32_t)key] = -1.0f;
    } else if (bin == binb) {
      uint32_t p = atomicAdd(&subcnt, 1u);
      if (p < SUB_CAP) sub[p] = key;
    }
  }
  __syncthreads();
  uint32_t c = subcnt < SUB_CAP ? subcnt : SUB_CAP;
  for (uint32_t s = t; s < c; s += 1024) {
    uint64_t key = sub[s];
    uint32_t rank = 0u;
    for (uint32_t j = 0; j < c; ++j) rank += (sub[j] < key) ? 1u : 0u;
    if (rank >= rneed) LBL[(uint32_t)key] = -1.0f;
  }
}

extern "C" void kernel_launch(void* const* d_in, const int* in_sizes, int n_in,
                              void* d_out, int out_size, void* d_ws, size_t ws_size,
                              hipStream_t stream) {
  (void)n_in; (void)out_size; (void)ws_size;
  const int N = in_sizes[0] / 4;  // 262144 anchors (multiple of 256)
  const int R = in_sizes[2] / 4;  // 100 gt boxes
  const int NB = N / 256;
  const float4* anc = (const float4*)d_in[0];
  const float* img = (const float*)d_in[1];
  const float4* gtb = (const float4*)d_in[2];
  float* LBL = (float*)d_out;
  float4* TGT = (float4*)((float*)d_out + N);

  uint8_t* ws = (uint8_t*)d_ws;
  uint32_t* counters = (uint32_t*)ws;                     // 16 u32
  uint32_t* flags = (uint32_t*)(ws + 64);                 // 64 u32
  uint32_t* gmaxu = (uint32_t*)(ws + 512);                // 128 u32
  float* gmaxf = (float*)(ws + 1024);                     // 128 f32
  uint32_t* pmax = (uint32_t*)(ws + 2048);                // NB*R u32 (~410 KB)
  size_t off = 2048 + (size_t)NB * R * 4;
  off = (off + 7) & ~(size_t)7;
  uint64_t* candList = (uint64_t*)(ws + off);             // CAND_CAP u64
  uint64_t* listF = (uint64_t*)(ws + off + CAND_CAP * 8); // FILT_CAP u64
  uint64_t* listB = (uint64_t*)(ws + off + CAND_CAP * 8 + FILT_CAP * 8);

  // Partitionable jax.random.split(key(42), 3): key_j = threefry((0,42),(0,j))
  uint32_t k1a, k1b, k2a, k2b, k3a, k3b;
  tf2x32(0u, 42u, 0u, 0u, k1a, k1b);
  tf2x32(0u, 42u, 0u, 1u, k2a, k2b);
  tf2x32(0u, 42u, 0u, 2u, k3a, k3b);

  k_init<<<1, 64, 0, stream>>>(counters, flags);
  k_main<<<NB, 256, 0, stream>>>(anc, img, gtb, N, R, pmax, LBL, TGT, counters);
  k_reduce<<<R, 256, 0, stream>>>(pmax, NB, R, gmaxu, gmaxf, flags);
  k_cand<<<NB, 256, 0, stream>>>(anc, img, gtb, N, R, flags, gmaxf, candList, counters,
                                 k1a, k1b);
  k_cand_select<<<1, 256, 0, stream>>>(candList, counters, LBL, R);
  k_gather<<<NB, 256, 0, stream>>>(LBL, N, 1.0f, counters, 1, 4, 128, 0, listF, k2a, k2b);
  k_sel<<<1, 1024, 0, stream>>>(listF, counters, 1, 4, 128, 0, LBL);
  k_gather<<<NB, 256, 0, stream>>>(LBL, N, 0.0f, counters, 2, 5, 256, 1, listB, k3a, k3b);
  k_sel<<<1, 1024, 0, stream>>>(listB, counters, 2, 5, 256, 1, LBL);
}